// Round 1
// baseline (442.492 us; speedup 1.0000x reference)
//
#include <hip/hip_runtime.h>
#include <math.h>

// ---------------------------------------------------------------------------
// TemporalSSMPatchwise: b=8,t=15,H=480,W=640, PS=8 -> hp=60,wp=80, n=4800
// d=64, P=32, pp=64.  N_seq = 38400.
// Transpose-free dataflow: weights are MFMA A-operands (pre-permuted rows),
// activations are B-operands.  With row-perm chan(nt,qd,r) =
// (nt>>1)*32 + qd*8 + (nt&1)*4 + r, the D-output register layout of one
// matmul IS the B-operand layout of the next (k-slot = kt*32+qd*8+j,
// identity on channel index).  No transpose, LN = 2 shfl_xor.
// MFMA 16x16x32 bf16: A[m=lane&15][k=qd*8+j], B[k=qd*8+j][n=lane&15],
// D: col=lane&15, row=qd*4+reg (m89/m91-verified).
//
// v2 (this round): k1 x-ingest restructured to cooperative DENSE staging
// through LDS (consecutive threads load consecutive 16B -> 1KB-contiguous
// per instruction) with double-buffer + 2-deep register prefetch, replacing
// the 32B-strided per-lane loads that were request-queue-limited at
// ~1.2 TB/s effective.  LDS: 16KB t-loop frags + 2x16KB stage buffers;
// head frags (32KB) swapped into the stage area after the scan.
// ---------------------------------------------------------------------------

typedef __attribute__((ext_vector_type(8))) short short8;
typedef __attribute__((ext_vector_type(4))) float f32x4;

#define MFMA16(a, b, c) __builtin_amdgcn_mfma_f32_16x16x32_bf16((a), (b), (c), 0, 0, 0)

__device__ __forceinline__ short f2bf(float f) {
  union { float f; unsigned u; } v; v.f = f;
  unsigned r = (v.u + 0x7fffu + ((v.u >> 16) & 1u)) >> 16;  // RNE
  return (short)r;
}
__device__ __forceinline__ float geluf(float x) {
  return 0.5f * x * (1.0f + erff(x * 0.70710678118654752f));
}
// pack two C-layout f32x4 tiles (2kt, 2kt+1) into one bf16 B-operand frag
__device__ __forceinline__ short8 packfrag(const f32x4& a, const f32x4& b) {
  short8 o;
  o[0] = f2bf(a[0]); o[1] = f2bf(a[1]); o[2] = f2bf(a[2]); o[3] = f2bf(a[3]);
  o[4] = f2bf(b[0]); o[5] = f2bf(b[1]); o[6] = f2bf(b[2]); o[7] = f2bf(b[3]);
  return o;
}
// weight-row permutation: A-row a = i*16+m  ->  actual channel
__device__ __forceinline__ int ecmap(int i, int m) {
  return (i >> 1) * 32 + (m >> 2) * 8 + (i & 1) * 4 + (m & 3);
}
// LDS stage-buffer swizzle: involution on byte bits [6:4], keyed by bits
// [8:7] (patch bits p[3:2]) and [12:11],[13] (row bits) which it leaves
// untouched.  Makes the fragment ds_read_b128 2-way (free) per 16-lane group.
__device__ __forceinline__ int swz(int b) {
  return b ^ (((b >> 2) ^ (b >> 6)) & 0x60) ^ (((b >> 3) ^ (b >> 9)) & 0x10);
}
__device__ __forceinline__ void bbar_factors(const float* Lre, const float* Lim,
                                             const float* lstep, int p,
                                             float& fre, float& fim) {
  float st = expf(lstep[p]);
  float lr = Lre[p], li = Lim[p];
  float er = expf(lr * st);
  float lbr = er * cosf(li * st), lbi = er * sinf(li * st);
  float u = lbr - 1.0f, v = lbi;
  float den = lr * lr + li * li;
  fre = (u * lr + v * li) / den;
  fim = (v * lr - u * li) / den;
}

// ---------------------------------------------------------------------------
// K0: pack 176 A-operand fragments (1 KB each) + bu0.
// ids: 0..7 W_embed | 8..15 Bbar'(g1-folded) | 16..23 Cc2(mask-folded)
//      24..39 W_enc | 40..47 W_dec | 48..175 W_out (natural rows)
// frag(i,kt) value[j] at lane(qd,m): A[i*16+m][k=kt*32+qd*8+j]
// ---------------------------------------------------------------------------
__global__ __launch_bounds__(256) void k0_prep(
    const float* __restrict__ W_embed, const float* __restrict__ g1,
    const float* __restrict__ be1, const float* __restrict__ Lre,
    const float* __restrict__ Lim, const float* __restrict__ Bre,
    const float* __restrict__ Bim, const float* __restrict__ Cre,
    const float* __restrict__ Cim, const float* __restrict__ lstep,
    const float* __restrict__ W_enc, const float* __restrict__ W_dec,
    const float* __restrict__ W_out, short* __restrict__ wimg,
    float* __restrict__ bu0) {
  const int bid = blockIdx.x;
  if (bid == 44) {  // bu0[q] = sum_d beta1[d] * Bbar_comp[p][d]
    int q = threadIdx.x;
    if (q < 64) {
      int c = q >> 5, p = q & 31;
      float fre, fim; bbar_factors(Lre, Lim, lstep, p, fre, fim);
      float s = 0.f;
      for (int d = 0; d < 64; ++d) {
        float br = Bre[p * 64 + d], bi = Bim[p * 64 + d];
        float val = c ? (fre * bi + fim * br) : (fre * br - fim * bi);
        s += be1[d] * val;
      }
      bu0[q] = s;
    }
    return;
  }
  const int w = threadIdx.x >> 6, lane = threadIdx.x & 63;
  const int m = lane & 15, qd = lane >> 4;
  const int f = bid * 4 + w;
  short v[8];
  if (f < 8) {
    int i = f >> 1, kt = f & 1, chan = ecmap(i, m), k0 = kt * 32 + qd * 8;
#pragma unroll
    for (int j = 0; j < 8; ++j) v[j] = f2bf(W_embed[chan * 64 + k0 + j]);
  } else if (f < 16) {
    int fi = f - 8, i = fi >> 1, kt = fi & 1;
    int comp = i & 1, p = (i >> 1) * 16 + m, d0 = kt * 32 + qd * 8;
    float fre, fim; bbar_factors(Lre, Lim, lstep, p, fre, fim);
#pragma unroll
    for (int j = 0; j < 8; ++j) {
      int d = d0 + j;
      float br = Bre[p * 64 + d], bi = Bim[p * 64 + d];
      float val = comp ? (fre * bi + fim * br) : (fre * br - fim * bi);
      v[j] = f2bf(g1[d] * val);
    }
  } else if (f < 24) {
    int fi = f - 16, i = fi >> 1, kt = fi & 1, chan = ecmap(i, m);
#pragma unroll
    for (int j = 0; j < 8; ++j) {
      int comp = j >> 2, p = kt * 16 + qd * 4 + (j & 3);
      float stp = expf(lstep[p]);
      float fr = stp * fabsf(Lim[p]) * (1.0f / 6.28318530717958648f);
      float msk = (fr < 0.5f) ? 1.f : 0.f;
      float val = comp ? -Cim[chan * 32 + p] * msk : Cre[chan * 32 + p] * msk;
      v[j] = f2bf(val);
    }
  } else if (f < 40) {
    int fi = f - 24, i = fi >> 1, kt = fi & 1;
    int row = (i < 4) ? ecmap(i, m) : 64 + ecmap(i - 4, m);
#pragma unroll
    for (int j = 0; j < 8; ++j) v[j] = f2bf(W_enc[row * 64 + kt * 32 + qd * 8 + j]);
  } else if (f < 48) {
    int fi = f - 40, i = fi >> 1, kt = fi & 1, row = ecmap(i, m);
#pragma unroll
    for (int j = 0; j < 8; ++j) v[j] = f2bf(W_dec[row * 64 + kt * 32 + qd * 8 + j]);
  } else {
    int fi = f - 48, i = fi >> 1, kt = fi & 1, row = i * 16 + m;  // natural
#pragma unroll
    for (int j = 0; j < 8; ++j) v[j] = f2bf(W_out[row * 64 + kt * 32 + qd * 8 + j]);
  }
  short8 sv;
#pragma unroll
  for (int j = 0; j < 8; ++j) sv[j] = v[j];
  *(short8*)&wimg[(f * 64 + lane) * 8] = sv;
}

// ---------------------------------------------------------------------------
// K1: embed -> LN1 -> Bu -> scan -> head(MLP) -> xlast^T.  256 thr = 4 waves,
// 16 seqs/wave, grid 600.  LDS: [0,16K) scan frags, [16K,48K) x stage dbuf
// (head frags swapped in after scan) -> 48KB -> 3 blocks/CU, 12 waves/CU.
// ---------------------------------------------------------------------------
__global__ __launch_bounds__(256, 3) void k1_fused(
    const float* __restrict__ x, const short* __restrict__ wimg_g,
    const float* __restrict__ bu0_g, const float* __restrict__ Lre,
    const float* __restrict__ Lim, const float* __restrict__ lstep,
    const float* __restrict__ g1, const float* __restrict__ be1,
    const float* __restrict__ bemb, const float* __restrict__ Dv,
    const float* __restrict__ g2, const float* __restrict__ be2,
    float* __restrict__ xlastT) {
  __shared__ __align__(16) char smem[49152];
#define WF(id) (*(const short8*)(smem + (id) * 1024 + lane * 16))

  const int tid = threadIdx.x;
  const int wv = tid >> 6, lane = tid & 63;
  const int s = lane & 15, qd = lane >> 4;

  // ---- issue scan-weight loads (16KB, frags 0..15) into regs ----
  float4 wreg[4];
  {
    const float4* src = (const float4*)wimg_g;
#pragma unroll
    for (int j = 0; j < 4; ++j) wreg[j] = src[j * 256 + tid];
  }

  // ---- dense staging setup: 4 chunks/thread, chunk c = r*128 + p*2 + h ----
  // chunk (r,p,h) = 16B of image row (ph(p)*8+r), patch p of block, half h.
  // consecutive c -> consecutive global 16B  => dense per instruction.
  int off[4], slot[4];
#pragma unroll
  for (int j = 0; j < 4; ++j) {
    int c = j * 256 + tid;                 // 0..1023
    int r = c >> 7, p = (c >> 1) & 63, h = c & 1;
    int seq = blockIdx.x * 64 + p;
    int b_i = seq / 4800, pr = seq % 4800;
    int ph = pr / 80, pw = pr % 80;
    off[j] = ((b_i * 15) * 480 + ph * 8 + r) * 640 + pw * 8 + h * 4;  // floats
    slot[j] = swz(c * 16);
  }
  // per-lane fragment read addresses (within a stage buffer)
  int rb[4];
#pragma unroll
  for (int kt = 0; kt < 2; ++kt)
#pragma unroll
    for (int h = 0; h < 2; ++h) {
      int b = (kt * 4 + qd) * 2048 + (wv * 16 + s) * 32 + h * 16;
      rb[kt * 2 + h] = swz(b);
    }

  const int sbase = (blockIdx.x * 4 + wv) * 16;

  int cb[4];
  f32x4 bec[4], bu0c[4];
#pragma unroll
  for (int nt = 0; nt < 4; ++nt) {
    cb[nt] = (nt >> 1) * 32 + qd * 8 + (nt & 1) * 4;
    bec[nt] = *(const f32x4*)(bemb + cb[nt]);
    bu0c[nt] = *(const f32x4*)(bu0_g + (nt & 1) * 32 + (nt >> 1) * 16 + qd * 4);
  }
  f32x4 lbr[2], lbi[2];
#pragma unroll
  for (int k = 0; k < 2; ++k)
#pragma unroll
    for (int r = 0; r < 4; ++r) {
      int p = k * 16 + qd * 4 + r;
      float st = expf(lstep[p]);
      float er = expf(Lre[p] * st);
      lbr[k][r] = er * cosf(Lim[p] * st);
      lbi[k][r] = er * sinf(Lim[p] * st);
    }

  // ---- prologue: stage t=0, prefetch t=1, write weights, one barrier ----
  float4 stg0[4], stgA[4];
#pragma unroll
  for (int j = 0; j < 4; ++j) stg0[j] = *(const float4*)(x + off[j]);
#pragma unroll
  for (int j = 0; j < 4; ++j) stgA[j] = *(const float4*)(x + off[j] + 307200);
  {
    float4* wdst = (float4*)smem;
#pragma unroll
    for (int j = 0; j < 4; ++j) wdst[j * 256 + tid] = wreg[j];
    char* b0 = smem + 16384;
#pragma unroll
    for (int j = 0; j < 4; ++j) *(float4*)(b0 + slot[j]) = stg0[j];
  }
  __syncthreads();

  const f32x4 zf = {0.f, 0.f, 0.f, 0.f};
  f32x4 state[4] = {zf, zf, zf, zf};
  f32x4 xh[4];
  f32x4 vcur[4];

  for (int t = 0; t < 15; ++t) {
    // prefetch t+2 into regs (in flight across this whole iteration)
    float4 stgB[4];
    if (t < 13) {
#pragma unroll
      for (int j = 0; j < 4; ++j)
        stgB[j] = *(const float4*)(x + off[j] + (t + 2) * 307200);
    }
    // fragment reads from current stage buffer
    const char* bufr = smem + 16384 + ((t & 1) << 14);
#pragma unroll
    for (int q = 0; q < 4; ++q) vcur[q] = *(const f32x4*)(bufr + rb[q]);

    short8 pa0 = packfrag(vcur[0], vcur[1]);
    short8 pa1 = packfrag(vcur[2], vcur[3]);
    f32x4 c1[4];
#pragma unroll
    for (int i = 0; i < 4; ++i) {
      f32x4 acc = MFMA16(WF(i * 2), pa0, zf);
      acc = MFMA16(WF(i * 2 + 1), pa1, acc);
      c1[i] = acc + bec[i];
    }
    float sm = 0.f, sq = 0.f;
#pragma unroll
    for (int nt = 0; nt < 4; ++nt)
#pragma unroll
      for (int i = 0; i < 4; ++i) { sm += c1[nt][i]; sq += c1[nt][i] * c1[nt][i]; }
    sm += __shfl_xor(sm, 16); sq += __shfl_xor(sq, 16);
    sm += __shfl_xor(sm, 32); sq += __shfl_xor(sq, 32);
    float mean = sm * 0.015625f;
    float rstd = rsqrtf(sq * 0.015625f - mean * mean + 1e-5f);
#pragma unroll
    for (int nt = 0; nt < 4; ++nt) xh[nt] = (c1[nt] - mean) * rstd;
    short8 xa0 = packfrag(xh[0], xh[1]);
    short8 xa1 = packfrag(xh[2], xh[3]);
#pragma unroll
    for (int k = 0; k < 2; ++k) {
      f32x4 re = state[2 * k], im = state[2 * k + 1];
      state[2 * k]     = lbr[k] * re - lbi[k] * im + bu0c[2 * k];
      state[2 * k + 1] = lbr[k] * im + lbi[k] * re + bu0c[2 * k + 1];
    }
#pragma unroll
    for (int i = 0; i < 4; ++i) {
      state[i] = MFMA16(WF(8 + i * 2), xa0, state[i]);
      state[i] = MFMA16(WF(8 + i * 2 + 1), xa1, state[i]);
    }

    // double-buffer handoff: write t+1 stage, rotate prefetch regs
    if (t < 14) {
      __syncthreads();  // everyone done reading buf[(t+1)&1] (iter t-1)
      char* bufw = smem + 16384 + (((t + 1) & 1) << 14);
#pragma unroll
      for (int j = 0; j < 4; ++j) *(float4*)(bufw + slot[j]) = stgA[j];
      __syncthreads();  // stage visible before iter t+1 reads
      if (t < 13) {
#pragma unroll
        for (int j = 0; j < 4; ++j) stgA[j] = stgB[j];
      }
    }
  }

  // ---- swap head frags (16..47, 32KB) into the stage-buffer space ----
  __syncthreads();
  {
    float4 hf[8];
    const float4* src = (const float4*)(wimg_g + 16 * 512);
#pragma unroll
    for (int j = 0; j < 8; ++j) hf[j] = src[j * 256 + tid];
    float4* dst = (float4*)(smem + 16384);
#pragma unroll
    for (int j = 0; j < 8; ++j) dst[j * 256 + tid] = hf[j];
  }
  __syncthreads();

  // ---- head at t = 14 ----
  f32x4 g1c[4], b1c[4], Dc[4], g2c[4], b2c[4];
#pragma unroll
  for (int nt = 0; nt < 4; ++nt) {
    g1c[nt] = *(const f32x4*)(g1 + cb[nt]);
    b1c[nt] = *(const f32x4*)(be1 + cb[nt]);
    Dc[nt] = *(const f32x4*)(Dv + cb[nt]);
    g2c[nt] = *(const f32x4*)(g2 + cb[nt]);
    b2c[nt] = *(const f32x4*)(be2 + cb[nt]);
  }
  f32x4 fxl[4];
#pragma unroll
  for (int nt = 0; nt < 4; ++nt) fxl[nt] = xh[nt] * g1c[nt] + b1c[nt];

  short8 xsa0 = packfrag(state[0], state[1]);
  short8 xsa1 = packfrag(state[2], state[3]);
  f32x4 xbv[4];
#pragma unroll
  for (int i = 0; i < 4; ++i) {
    f32x4 acc = fxl[i] * Dc[i];
    acc = MFMA16(WF(16 + i * 2), xsa0, acc);
    acc = MFMA16(WF(16 + i * 2 + 1), xsa1, acc);
#pragma unroll
    for (int r = 0; r < 4; ++r) xbv[i][r] = geluf(acc[r]) + fxl[i][r];
  }
  float sm2 = 0.f, sq2 = 0.f;
#pragma unroll
  for (int nt = 0; nt < 4; ++nt)
#pragma unroll
    for (int i = 0; i < 4; ++i) { sm2 += xbv[nt][i]; sq2 += xbv[nt][i] * xbv[nt][i]; }
  sm2 += __shfl_xor(sm2, 16); sq2 += __shfl_xor(sq2, 16);
  sm2 += __shfl_xor(sm2, 32); sq2 += __shfl_xor(sq2, 32);
  float mean2 = sm2 * 0.015625f;
  float rstd2 = rsqrtf(sq2 * 0.015625f - mean2 * mean2 + 1e-5f);
  f32x4 fx2[4];
#pragma unroll
  for (int nt = 0; nt < 4; ++nt)
    fx2[nt] = (xbv[nt] - mean2) * rstd2 * g2c[nt] + b2c[nt];

  short8 fa0 = packfrag(fx2[0], fx2[1]);
  short8 fa1 = packfrag(fx2[2], fx2[3]);
  f32x4 e[8];
#pragma unroll
  for (int i = 0; i < 8; ++i) {
    f32x4 acc = MFMA16(WF(24 + i * 2), fa0, zf);
    e[i] = MFMA16(WF(24 + i * 2 + 1), fa1, acc);
  }
  f32x4 hv[4];
#pragma unroll
  for (int nt = 0; nt < 4; ++nt)
#pragma unroll
    for (int i = 0; i < 4; ++i) hv[nt][i] = e[nt][i] * geluf(e[nt + 4][i]);

  short8 ha0 = packfrag(hv[0], hv[1]);
  short8 ha1 = packfrag(hv[2], hv[3]);
  f32x4 xo[4];
#pragma unroll
  for (int i = 0; i < 4; ++i) {
    f32x4 acc = fx2[i];
    acc = MFMA16(WF(40 + i * 2), ha0, acc);
    xo[i] = MFMA16(WF(40 + i * 2 + 1), ha1, acc);
  }
  // store transposed: xlastT[d][seq], d-slot identity = kt*32+qd*8+j
#pragma unroll
  for (int kt = 0; kt < 2; ++kt)
#pragma unroll
    for (int j = 0; j < 8; ++j)
      xlastT[(kt * 32 + qd * 8 + j) * 38400 + sbase + s] = xo[2 * kt + (j >> 2)][j & 3];
#undef WF
}

// ---------------------------------------------------------------------------
// K2: LN3 + W_out(A-op) x z^T + b_out -> float4 pixel-shuffle stores.
// 256 thr = 4 waves x 16 seqs; block covers 64 seqs x 256 out-rows.
// ---------------------------------------------------------------------------
__global__ __launch_bounds__(256) void k2_head(
    const float* __restrict__ xlastT, const short* __restrict__ wout_img,
    const float* __restrict__ g3, const float* __restrict__ be3,
    const float* __restrict__ b_out, float* __restrict__ y) {
  __shared__ short wo[32 * 512];
  const int nqb = blockIdx.x & 3;
  const int mblk = blockIdx.x >> 2;
  {
    float4* dst = (float4*)wo;
    const float4* src = (const float4*)(wout_img + nqb * 32 * 512);
    for (int i = threadIdx.x; i < 2048; i += 256) dst[i] = src[i];
  }
  __syncthreads();
  const int wv = threadIdx.x >> 6, lane = threadIdx.x & 63;
  const int s = lane & 15, qd = lane >> 4;
  const int sbase = mblk * 64 + wv * 16;
  const int seq = sbase + s;
  const int nq0 = nqb * 256;

  float vals[2][8];
#pragma unroll
  for (int kt = 0; kt < 2; ++kt)
#pragma unroll
    for (int j = 0; j < 8; ++j)
      vals[kt][j] = xlastT[(kt * 32 + qd * 8 + j) * 38400 + seq];
  float sm = 0.f, sq = 0.f;
#pragma unroll
  for (int kt = 0; kt < 2; ++kt)
#pragma unroll
    for (int j = 0; j < 8; ++j) { sm += vals[kt][j]; sq += vals[kt][j] * vals[kt][j]; }
  sm += __shfl_xor(sm, 16); sq += __shfl_xor(sq, 16);
  sm += __shfl_xor(sm, 32); sq += __shfl_xor(sq, 32);
  float mean = sm * 0.015625f;
  float rstd = rsqrtf(sq * 0.015625f - mean * mean + 1e-5f);

  short8 zb[2];
#pragma unroll
  for (int kt = 0; kt < 2; ++kt) {
    f32x4 ga = *(const f32x4*)(g3 + kt * 32 + qd * 8);
    f32x4 gb = *(const f32x4*)(g3 + kt * 32 + qd * 8 + 4);
    f32x4 ba = *(const f32x4*)(be3 + kt * 32 + qd * 8);
    f32x4 bb = *(const f32x4*)(be3 + kt * 32 + qd * 8 + 4);
#pragma unroll
    for (int j = 0; j < 4; ++j) {
      zb[kt][j] = f2bf((vals[kt][j] - mean) * rstd * ga[j] + ba[j]);
      zb[kt][j + 4] = f2bf((vals[kt][j + 4] - mean) * rstd * gb[j] + bb[j]);
    }
  }
  const int bi2 = seq / 4800, prr = seq % 4800;
  const int phh = prr / 80, pww = prr % 80;
  const int obase = (bi2 * 16 * 480 + phh * 8) * 640 + pww * 8;

#pragma unroll
  for (int nt = 0; nt < 16; ++nt) {
    int o0 = nq0 + nt * 16 + qd * 4;
    f32x4 acc = *(const f32x4*)(b_out + o0);
    acc = MFMA16(*(const short8*)&wo[(nt * 2 + 0) * 512 + lane * 8], zb[0], acc);
    acc = MFMA16(*(const short8*)&wo[(nt * 2 + 1) * 512 + lane * 8], zb[1], acc);
    int c = o0 >> 6, pi = (o0 >> 3) & 7, pj = o0 & 7;
    *(f32x4*)&y[obase + c * 307200 + pi * 640 + pj] = acc;
  }
}

// ---------------------------------------------------------------------------
extern "C" void kernel_launch(void* const* d_in, const int* in_sizes, int n_in,
                              void* d_out, int out_size, void* d_ws, size_t ws_size,
                              hipStream_t stream) {
  const float* x       = (const float*)d_in[0];
  const float* W_embed = (const float*)d_in[1];
  const float* b_embed = (const float*)d_in[2];
  const float* g1      = (const float*)d_in[3];
  const float* beta1   = (const float*)d_in[4];
  const float* Lre     = (const float*)d_in[5];
  const float* Lim     = (const float*)d_in[6];
  const float* Bre     = (const float*)d_in[7];
  const float* Bim     = (const float*)d_in[8];
  const float* Cre     = (const float*)d_in[9];
  const float* Cim     = (const float*)d_in[10];
  const float* Dv      = (const float*)d_in[11];
  const float* lstep   = (const float*)d_in[12];
  const float* g2      = (const float*)d_in[13];
  const float* beta2   = (const float*)d_in[14];
  const float* W_enc   = (const float*)d_in[15];
  const float* W_dec   = (const float*)d_in[16];
  const float* g3      = (const float*)d_in[17];
  const float* beta3   = (const float*)d_in[18];
  const float* W_out   = (const float*)d_in[19];
  const float* b_out   = (const float*)d_in[20];
  float* y = (float*)d_out;

  short* wimg = (short*)d_ws;                          // 176 KB frag images
  float* bu0 = (float*)((char*)d_ws + 176 * 1024);     // 256 B
  float* xlastT = (float*)((char*)d_ws + 180 * 1024);  // 64 x 38400 f32

  k0_prep<<<dim3(45), dim3(256), 0, stream>>>(W_embed, g1, beta1, Lre, Lim,
                                              Bre, Bim, Cre, Cim, lstep,
                                              W_enc, W_dec, W_out, wimg, bu0);
  k1_fused<<<dim3(600), dim3(256), 0, stream>>>(x, wimg, bu0, Lre, Lim, lstep,
                                                g1, beta1, b_embed, Dv, g2,
                                                beta2, xlastT);
  k2_head<<<dim3(2400), dim3(256), 0, stream>>>(xlastT, wimg + 48 * 512, g3,
                                                beta3, b_out, y);
}

// Round 3
// 342.257 us; speedup vs baseline: 1.2929x; 1.2929x over previous
//
#include <hip/hip_runtime.h>
#include <math.h>

// ---------------------------------------------------------------------------
// TemporalSSMPatchwise: b=8,t=15,H=480,W=640, PS=8 -> hp=60,wp=80, n=4800
// d=64, P=32, pp=64.  N_seq = 38400.
// Transpose-free dataflow: weights are MFMA A-operands (pre-permuted rows),
// activations are B-operands.  With row-perm chan(nt,qd,r) =
// (nt>>1)*32 + qd*8 + (nt&1)*4 + r, the D-output register layout of one
// matmul IS the B-operand layout of the next (k-slot = kt*32+qd*8+j,
// identity on channel index).  No transpose, LN = 2 shfl_xor.
// MFMA 16x16x32 bf16: A[m=lane&15][k=qd*8+j], B[k=qd*8+j][n=lane&15],
// D: col=lane&15, row=qd*4+reg (m89/m91-verified).
//
// v3b: resubmit of v3 (container infra failure, no kernel result) with one
// hardening: prologue drains vmcnt(0) (v3's vmcnt(4) assumed STAGE issue
// order across two intrinsics in the same fence window; LLVM may reorder).
// x-ingest = dense cooperative global->LDS via global_load_lds width=16
// (zero VGPR round-trip; v2's register prefetch spilled: 252MB writebacks).
// Linear LDS dest + inverse-swizzled per-lane global source (swz involution)
// + swizzled ds_read (rule-21).  2-phase pipeline, counted vmcnt in steady
// state, raw s_barrier.  LDS: 16KB frags + 2x16KB stage dbuf = 48KB,
// 3 blocks/CU; head frags swapped into stage area after the scan.
// ---------------------------------------------------------------------------

typedef __attribute__((ext_vector_type(8))) short short8;
typedef __attribute__((ext_vector_type(4))) float f32x4;

#define MFMA16(a, b, c) __builtin_amdgcn_mfma_f32_16x16x32_bf16((a), (b), (c), 0, 0, 0)

__device__ __forceinline__ short f2bf(float f) {
  union { float f; unsigned u; } v; v.f = f;
  unsigned r = (v.u + 0x7fffu + ((v.u >> 16) & 1u)) >> 16;  // RNE
  return (short)r;
}
__device__ __forceinline__ float geluf(float x) {
  return 0.5f * x * (1.0f + erff(x * 0.70710678118654752f));
}
// pack two C-layout f32x4 tiles (2kt, 2kt+1) into one bf16 B-operand frag
__device__ __forceinline__ short8 packfrag(const f32x4& a, const f32x4& b) {
  short8 o;
  o[0] = f2bf(a[0]); o[1] = f2bf(a[1]); o[2] = f2bf(a[2]); o[3] = f2bf(a[3]);
  o[4] = f2bf(b[0]); o[5] = f2bf(b[1]); o[6] = f2bf(b[2]); o[7] = f2bf(b[3]);
  return o;
}
// weight-row permutation: A-row a = i*16+m  ->  actual channel
__device__ __forceinline__ int ecmap(int i, int m) {
  return (i >> 1) * 32 + (m >> 2) * 8 + (i & 1) * 4 + (m & 3);
}
// Stage-buffer swizzle: involution on byte bits [6:4] keyed by bits
// {7,8,11,12,13} (untouched).  Spreads the per-lane fragment ds_read_b128
// across banks.  Involution => LDS[L] := data[swz(L)] gives
// LDS[swz(b)] == data[b]: linear global_load_lds dest + swizzled source
// + swizzled read is self-consistent (rule 21).
__device__ __forceinline__ int swz(int b) {
  return b ^ (((b >> 2) ^ (b >> 6)) & 0x60) ^ (((b >> 3) ^ (b >> 9)) & 0x10);
}
__device__ __forceinline__ void bbar_factors(const float* Lre, const float* Lim,
                                             const float* lstep, int p,
                                             float& fre, float& fim) {
  float st = expf(lstep[p]);
  float lr = Lre[p], li = Lim[p];
  float er = expf(lr * st);
  float lbr = er * cosf(li * st), lbi = er * sinf(li * st);
  float u = lbr - 1.0f, v = lbi;
  float den = lr * lr + li * li;
  fre = (u * lr + v * li) / den;
  fim = (v * lr - u * li) / den;
}

// ---------------------------------------------------------------------------
// K0: pack 176 A-operand fragments (1 KB each) + bu0.
// ids: 0..7 W_embed | 8..15 Bbar'(g1-folded) | 16..23 Cc2(mask-folded)
//      24..39 W_enc | 40..47 W_dec | 48..175 W_out (natural rows)
// frag(i,kt) value[j] at lane(qd,m): A[i*16+m][k=kt*32+qd*8+j]
// ---------------------------------------------------------------------------
__global__ __launch_bounds__(256) void k0_prep(
    const float* __restrict__ W_embed, const float* __restrict__ g1,
    const float* __restrict__ be1, const float* __restrict__ Lre,
    const float* __restrict__ Lim, const float* __restrict__ Bre,
    const float* __restrict__ Bim, const float* __restrict__ Cre,
    const float* __restrict__ Cim, const float* __restrict__ lstep,
    const float* __restrict__ W_enc, const float* __restrict__ W_dec,
    const float* __restrict__ W_out, short* __restrict__ wimg,
    float* __restrict__ bu0) {
  const int bid = blockIdx.x;
  if (bid == 44) {  // bu0[q] = sum_d beta1[d] * Bbar_comp[p][d]
    int q = threadIdx.x;
    if (q < 64) {
      int c = q >> 5, p = q & 31;
      float fre, fim; bbar_factors(Lre, Lim, lstep, p, fre, fim);
      float s = 0.f;
      for (int d = 0; d < 64; ++d) {
        float br = Bre[p * 64 + d], bi = Bim[p * 64 + d];
        float val = c ? (fre * bi + fim * br) : (fre * br - fim * bi);
        s += be1[d] * val;
      }
      bu0[q] = s;
    }
    return;
  }
  const int w = threadIdx.x >> 6, lane = threadIdx.x & 63;
  const int m = lane & 15, qd = lane >> 4;
  const int f = bid * 4 + w;
  short v[8];
  if (f < 8) {
    int i = f >> 1, kt = f & 1, chan = ecmap(i, m), k0 = kt * 32 + qd * 8;
#pragma unroll
    for (int j = 0; j < 8; ++j) v[j] = f2bf(W_embed[chan * 64 + k0 + j]);
  } else if (f < 16) {
    int fi = f - 8, i = fi >> 1, kt = fi & 1;
    int comp = i & 1, p = (i >> 1) * 16 + m, d0 = kt * 32 + qd * 8;
    float fre, fim; bbar_factors(Lre, Lim, lstep, p, fre, fim);
#pragma unroll
    for (int j = 0; j < 8; ++j) {
      int d = d0 + j;
      float br = Bre[p * 64 + d], bi = Bim[p * 64 + d];
      float val = comp ? (fre * bi + fim * br) : (fre * br - fim * bi);
      v[j] = f2bf(g1[d] * val);
    }
  } else if (f < 24) {
    int fi = f - 16, i = fi >> 1, kt = fi & 1, chan = ecmap(i, m);
#pragma unroll
    for (int j = 0; j < 8; ++j) {
      int comp = j >> 2, p = kt * 16 + qd * 4 + (j & 3);
      float stp = expf(lstep[p]);
      float fr = stp * fabsf(Lim[p]) * (1.0f / 6.28318530717958648f);
      float msk = (fr < 0.5f) ? 1.f : 0.f;
      float val = comp ? -Cim[chan * 32 + p] * msk : Cre[chan * 32 + p] * msk;
      v[j] = f2bf(val);
    }
  } else if (f < 40) {
    int fi = f - 24, i = fi >> 1, kt = fi & 1;
    int row = (i < 4) ? ecmap(i, m) : 64 + ecmap(i - 4, m);
#pragma unroll
    for (int j = 0; j < 8; ++j) v[j] = f2bf(W_enc[row * 64 + kt * 32 + qd * 8 + j]);
  } else if (f < 48) {
    int fi = f - 40, i = fi >> 1, kt = fi & 1, row = ecmap(i, m);
#pragma unroll
    for (int j = 0; j < 8; ++j) v[j] = f2bf(W_dec[row * 64 + kt * 32 + qd * 8 + j]);
  } else {
    int fi = f - 48, i = fi >> 1, kt = fi & 1, row = i * 16 + m;  // natural
#pragma unroll
    for (int j = 0; j < 8; ++j) v[j] = f2bf(W_out[row * 64 + kt * 32 + qd * 8 + j]);
  }
  short8 sv;
#pragma unroll
  for (int j = 0; j < 8; ++j) sv[j] = v[j];
  *(short8*)&wimg[(f * 64 + lane) * 8] = sv;
}

// ---------------------------------------------------------------------------
// K1: embed -> LN1 -> Bu -> scan -> head(MLP) -> xlast^T.  256 thr = 4 waves,
// 16 seqs/wave, grid 600.  LDS: [0,16K) scan frags, [16K,48K) x stage dbuf
// (head frags swapped in after scan) -> 48KB -> 3 blocks/CU.
// ---------------------------------------------------------------------------
__global__ __launch_bounds__(256) void k1_fused(
    const float* __restrict__ x, const short* __restrict__ wimg_g,
    const float* __restrict__ bu0_g, const float* __restrict__ Lre,
    const float* __restrict__ Lim, const float* __restrict__ lstep,
    const float* __restrict__ g1, const float* __restrict__ be1,
    const float* __restrict__ bemb, const float* __restrict__ Dv,
    const float* __restrict__ g2, const float* __restrict__ be2,
    float* __restrict__ xlastT) {
  __shared__ __align__(16) char smem[49152];
#define WF(id) (*(const short8*)(smem + (id) * 1024 + lane * 16))

  const int tid = threadIdx.x;
  const int wv = tid >> 6, lane = tid & 63;
  const int s = lane & 15, qd = lane >> 4;

  // ---- scan-weight loads (16KB, frags 0..15) into regs (issued first) ----
  float4 wreg[4];
  {
    const float4* src = (const float4*)wimg_g;
#pragma unroll
    for (int j = 0; j < 4; ++j) wreg[j] = src[j * 256 + tid];
  }

  // ---- per-lane constants (all global reads before staging starts) ----
  int cb[4];
  f32x4 bec[4], bu0c[4];
#pragma unroll
  for (int nt = 0; nt < 4; ++nt) {
    cb[nt] = (nt >> 1) * 32 + qd * 8 + (nt & 1) * 4;
    bec[nt] = *(const f32x4*)(bemb + cb[nt]);
    bu0c[nt] = *(const f32x4*)(bu0_g + (nt & 1) * 32 + (nt >> 1) * 16 + qd * 4);
  }
  f32x4 lbr[2], lbi[2];
#pragma unroll
  for (int k = 0; k < 2; ++k)
#pragma unroll
    for (int r = 0; r < 4; ++r) {
      int p = k * 16 + qd * 4 + r;
      float st = expf(lstep[p]);
      float er = expf(Lre[p] * st);
      lbr[k][r] = er * cosf(Lim[p] * st);
      lbi[k][r] = er * sinf(Lim[p] * st);
    }

  // ---- staging geometry ----
  // Logical byte b of a 16KB tile: bits[3:0] within-16B, bit4=h (8B half),
  // bits[10:5]=p (patch in block), bits[13:11]=r (row in patch).
  // Wave wv, instr j writes LDS linear bytes L=(wv*4+j)*1024 + lane*16;
  // source for that lane is logical chunk swz(L) (involution).
  int off[4];
#pragma unroll
  for (int j = 0; j < 4; ++j) {
    int L = (wv * 4 + j) * 1024 + lane * 16;
    int b = swz(L);
    int c = b >> 4;
    int r = c >> 7, p = (c >> 1) & 63, h = c & 1;
    int seq = blockIdx.x * 64 + p;
    int b_i = seq / 4800, pr = seq % 4800;
    int ph = pr / 80, pw = pr % 80;
    off[j] = ((b_i * 15) * 480 + ph * 8 + r) * 640 + pw * 8 + h * 4;  // floats
  }
  // per-lane fragment read addresses (within a stage buffer), swizzled
  int rb[4];
#pragma unroll
  for (int kt = 0; kt < 2; ++kt)
#pragma unroll
    for (int h = 0; h < 2; ++h) {
      int b = (kt * 4 + qd) * 2048 + (wv * 16 + s) * 32 + h * 16;
      rb[kt * 2 + h] = swz(b);
    }

#define STAGE(bufofs, tt)                                                     \
  {                                                                           \
    const float* gsrc = x + (tt) * 307200;                                    \
    char* lb = smem + (bufofs) + wv * 4096;                                   \
    _Pragma("unroll") for (int j = 0; j < 4; ++j)                             \
        __builtin_amdgcn_global_load_lds(                                     \
            (const __attribute__((address_space(1))) void*)(gsrc + off[j]),   \
            (__attribute__((address_space(3))) void*)(lb + j * 1024),         \
            16, 0, 0);                                                        \
  }

  const int sbase = (blockIdx.x * 4 + wv) * 16;

  // ---- prologue: stage t=0 and t=1 (async), weights -> LDS, full drain ----
  STAGE(16384, 0);
  STAGE(32768, 1);
  {
    float4* wdst = (float4*)smem;
#pragma unroll
    for (int j = 0; j < 4; ++j) wdst[j * 256 + tid] = wreg[j];
  }
  // vmcnt(0): order of the two prologue STAGEs is not guaranteed by the
  // compiler, so a counted wait here could leave t=0 loads in flight.
  asm volatile("s_waitcnt vmcnt(0) lgkmcnt(0)" ::: "memory");
  __builtin_amdgcn_s_barrier();

  const f32x4 zf = {0.f, 0.f, 0.f, 0.f};
  f32x4 state[4] = {zf, zf, zf, zf};
  f32x4 xh[4];

  for (int t = 0; t < 15; ++t) {
    // read this tile's fragments from buf[t&1]
    const char* bufr = smem + 16384 + ((t & 1) << 14);
    f32x4 vcur[4];
#pragma unroll
    for (int q = 0; q < 4; ++q) vcur[q] = *(const f32x4*)(bufr + rb[q]);
    asm volatile("s_waitcnt lgkmcnt(0)" ::: "memory");  // reads retired
    __builtin_amdgcn_s_barrier();  // B1: all waves done reading buf[t&1]
    if (t < 13) STAGE(16384 + ((t & 1) << 14), t + 2);  // overwrite, async

    short8 pa0 = packfrag(vcur[0], vcur[1]);
    short8 pa1 = packfrag(vcur[2], vcur[3]);
    f32x4 c1[4];
#pragma unroll
    for (int i = 0; i < 4; ++i) {
      f32x4 acc = MFMA16(WF(i * 2), pa0, zf);
      acc = MFMA16(WF(i * 2 + 1), pa1, acc);
      c1[i] = acc + bec[i];
    }
    float sm = 0.f, sq = 0.f;
#pragma unroll
    for (int nt = 0; nt < 4; ++nt)
#pragma unroll
      for (int i = 0; i < 4; ++i) { sm += c1[nt][i]; sq += c1[nt][i] * c1[nt][i]; }
    sm += __shfl_xor(sm, 16); sq += __shfl_xor(sq, 16);
    sm += __shfl_xor(sm, 32); sq += __shfl_xor(sq, 32);
    float mean = sm * 0.015625f;
    float rstd = rsqrtf(sq * 0.015625f - mean * mean + 1e-5f);
#pragma unroll
    for (int nt = 0; nt < 4; ++nt) xh[nt] = (c1[nt] - mean) * rstd;
    short8 xa0 = packfrag(xh[0], xh[1]);
    short8 xa1 = packfrag(xh[2], xh[3]);
#pragma unroll
    for (int k = 0; k < 2; ++k) {
      f32x4 re = state[2 * k], im = state[2 * k + 1];
      state[2 * k]     = lbr[k] * re - lbi[k] * im + bu0c[2 * k];
      state[2 * k + 1] = lbr[k] * im + lbi[k] * re + bu0c[2 * k + 1];
    }
#pragma unroll
    for (int i = 0; i < 4; ++i) {
      state[i] = MFMA16(WF(8 + i * 2), xa0, state[i]);
      state[i] = MFMA16(WF(8 + i * 2 + 1), xa1, state[i]);
    }

    // before next iter reads buf[(t+1)&1]: own stage(t+1) loads done, then
    // barrier => all waves' stage(t+1) done.  Counted: stage(t+2)'s 4 loads
    // stay in flight (never drain to 0 in steady state).  Only one STAGE per
    // fence window, so the count is order-safe here.
    if (t < 14) {
      if (t < 13) asm volatile("s_waitcnt vmcnt(4)" ::: "memory");
      else        asm volatile("s_waitcnt vmcnt(0)" ::: "memory");
      __builtin_amdgcn_s_barrier();  // B2
    }
  }
#undef STAGE

  // ---- swap head frags (16..47, 32KB) into the stage-buffer space ----
  __syncthreads();
  {
    float4 hf[8];
    const float4* src = (const float4*)(wimg_g + 16 * 512);
#pragma unroll
    for (int j = 0; j < 8; ++j) hf[j] = src[j * 256 + tid];
    float4* dst = (float4*)(smem + 16384);
#pragma unroll
    for (int j = 0; j < 8; ++j) dst[j * 256 + tid] = hf[j];
  }
  __syncthreads();

  // ---- head at t = 14 ----
  f32x4 g1c[4], b1c[4], Dc[4], g2c[4], b2c[4];
#pragma unroll
  for (int nt = 0; nt < 4; ++nt) {
    g1c[nt] = *(const f32x4*)(g1 + cb[nt]);
    b1c[nt] = *(const f32x4*)(be1 + cb[nt]);
    Dc[nt] = *(const f32x4*)(Dv + cb[nt]);
    g2c[nt] = *(const f32x4*)(g2 + cb[nt]);
    b2c[nt] = *(const f32x4*)(be2 + cb[nt]);
  }
  f32x4 fxl[4];
#pragma unroll
  for (int nt = 0; nt < 4; ++nt) fxl[nt] = xh[nt] * g1c[nt] + b1c[nt];

  short8 xsa0 = packfrag(state[0], state[1]);
  short8 xsa1 = packfrag(state[2], state[3]);
  f32x4 xbv[4];
#pragma unroll
  for (int i = 0; i < 4; ++i) {
    f32x4 acc = fxl[i] * Dc[i];
    acc = MFMA16(WF(16 + i * 2), xsa0, acc);
    acc = MFMA16(WF(16 + i * 2 + 1), xsa1, acc);
#pragma unroll
    for (int r = 0; r < 4; ++r) xbv[i][r] = geluf(acc[r]) + fxl[i][r];
  }
  float sm2 = 0.f, sq2 = 0.f;
#pragma unroll
  for (int nt = 0; nt < 4; ++nt)
#pragma unroll
    for (int i = 0; i < 4; ++i) { sm2 += xbv[nt][i]; sq2 += xbv[nt][i] * xbv[nt][i]; }
  sm2 += __shfl_xor(sm2, 16); sq2 += __shfl_xor(sq2, 16);
  sm2 += __shfl_xor(sm2, 32); sq2 += __shfl_xor(sq2, 32);
  float mean2 = sm2 * 0.015625f;
  float rstd2 = rsqrtf(sq2 * 0.015625f - mean2 * mean2 + 1e-5f);
  f32x4 fx2[4];
#pragma unroll
  for (int nt = 0; nt < 4; ++nt)
    fx2[nt] = (xbv[nt] - mean2) * rstd2 * g2c[nt] + b2c[nt];

  short8 fa0 = packfrag(fx2[0], fx2[1]);
  short8 fa1 = packfrag(fx2[2], fx2[3]);
  f32x4 e[8];
#pragma unroll
  for (int i = 0; i < 8; ++i) {
    f32x4 acc = MFMA16(WF(24 + i * 2), fa0, zf);
    e[i] = MFMA16(WF(24 + i * 2 + 1), fa1, acc);
  }
  f32x4 hv[4];
#pragma unroll
  for (int nt = 0; nt < 4; ++nt)
#pragma unroll
    for (int i = 0; i < 4; ++i) hv[nt][i] = e[nt][i] * geluf(e[nt + 4][i]);

  short8 ha0 = packfrag(hv[0], hv[1]);
  short8 ha1 = packfrag(hv[2], hv[3]);
  f32x4 xo[4];
#pragma unroll
  for (int i = 0; i < 4; ++i) {
    f32x4 acc = fx2[i];
    acc = MFMA16(WF(40 + i * 2), ha0, acc);
    xo[i] = MFMA16(WF(40 + i * 2 + 1), ha1, acc);
  }
  // store transposed: xlastT[d][seq], d-slot identity = kt*32+qd*8+j
#pragma unroll
  for (int kt = 0; kt < 2; ++kt)
#pragma unroll
    for (int j = 0; j < 8; ++j)
      xlastT[(kt * 32 + qd * 8 + j) * 38400 + sbase + s] = xo[2 * kt + (j >> 2)][j & 3];
#undef WF
}

// ---------------------------------------------------------------------------
// K2: LN3 + W_out(A-op) x z^T + b_out -> float4 pixel-shuffle stores.
// 256 thr = 4 waves x 16 seqs; block covers 64 seqs x 256 out-rows.
// ---------------------------------------------------------------------------
__global__ __launch_bounds__(256) void k2_head(
    const float* __restrict__ xlastT, const short* __restrict__ wout_img,
    const float* __restrict__ g3, const float* __restrict__ be3,
    const float* __restrict__ b_out, float* __restrict__ y) {
  __shared__ short wo[32 * 512];
  const int nqb = blockIdx.x & 3;
  const int mblk = blockIdx.x >> 2;
  {
    float4* dst = (float4*)wo;
    const float4* src = (const float4*)(wout_img + nqb * 32 * 512);
    for (int i = threadIdx.x; i < 2048; i += 256) dst[i] = src[i];
  }
  __syncthreads();
  const int wv = threadIdx.x >> 6, lane = threadIdx.x & 63;
  const int s = lane & 15, qd = lane >> 4;
  const int sbase = mblk * 64 + wv * 16;
  const int seq = sbase + s;
  const int nq0 = nqb * 256;

  float vals[2][8];
#pragma unroll
  for (int kt = 0; kt < 2; ++kt)
#pragma unroll
    for (int j = 0; j < 8; ++j)
      vals[kt][j] = xlastT[(kt * 32 + qd * 8 + j) * 38400 + seq];
  float sm = 0.f, sq = 0.f;
#pragma unroll
  for (int kt = 0; kt < 2; ++kt)
#pragma unroll
    for (int j = 0; j < 8; ++j) { sm += vals[kt][j]; sq += vals[kt][j] * vals[kt][j]; }
  sm += __shfl_xor(sm, 16); sq += __shfl_xor(sq, 16);
  sm += __shfl_xor(sm, 32); sq += __shfl_xor(sq, 32);
  float mean = sm * 0.015625f;
  float rstd = rsqrtf(sq * 0.015625f - mean * mean + 1e-5f);

  short8 zb[2];
#pragma unroll
  for (int kt = 0; kt < 2; ++kt) {
    f32x4 ga = *(const f32x4*)(g3 + kt * 32 + qd * 8);
    f32x4 gb = *(const f32x4*)(g3 + kt * 32 + qd * 8 + 4);
    f32x4 ba = *(const f32x4*)(be3 + kt * 32 + qd * 8);
    f32x4 bb = *(const f32x4*)(be3 + kt * 32 + qd * 8 + 4);
#pragma unroll
    for (int j = 0; j < 4; ++j) {
      zb[kt][j] = f2bf((vals[kt][j] - mean) * rstd * ga[j] + ba[j]);
      zb[kt][j + 4] = f2bf((vals[kt][j + 4] - mean) * rstd * gb[j] + bb[j]);
    }
  }
  const int bi2 = seq / 4800, prr = seq % 4800;
  const int phh = prr / 80, pww = prr % 80;
  const int obase = (bi2 * 16 * 480 + phh * 8) * 640 + pww * 8;

#pragma unroll
  for (int nt = 0; nt < 16; ++nt) {
    int o0 = nq0 + nt * 16 + qd * 4;
    f32x4 acc = *(const f32x4*)(b_out + o0);
    acc = MFMA16(*(const short8*)&wo[(nt * 2 + 0) * 512 + lane * 8], zb[0], acc);
    acc = MFMA16(*(const short8*)&wo[(nt * 2 + 1) * 512 + lane * 8], zb[1], acc);
    int c = o0 >> 6, pi = (o0 >> 3) & 7, pj = o0 & 7;
    *(f32x4*)&y[obase + c * 307200 + pi * 640 + pj] = acc;
  }
}

// ---------------------------------------------------------------------------
extern "C" void kernel_launch(void* const* d_in, const int* in_sizes, int n_in,
                              void* d_out, int out_size, void* d_ws, size_t ws_size,
                              hipStream_t stream) {
  const float* x       = (const float*)d_in[0];
  const float* W_embed = (const float*)d_in[1];
  const float* b_embed = (const float*)d_in[2];
  const float* g1      = (const float*)d_in[3];
  const float* beta1   = (const float*)d_in[4];
  const float* Lre     = (const float*)d_in[5];
  const float* Lim     = (const float*)d_in[6];
  const float* Bre     = (const float*)d_in[7];
  const float* Bim     = (const float*)d_in[8];
  const float* Cre     = (const float*)d_in[9];
  const float* Cim     = (const float*)d_in[10];
  const float* Dv      = (const float*)d_in[11];
  const float* lstep   = (const float*)d_in[12];
  const float* g2      = (const float*)d_in[13];
  const float* beta2   = (const float*)d_in[14];
  const float* W_enc   = (const float*)d_in[15];
  const float* W_dec   = (const float*)d_in[16];
  const float* g3      = (const float*)d_in[17];
  const float* beta3   = (const float*)d_in[18];
  const float* W_out   = (const float*)d_in[19];
  const float* b_out   = (const float*)d_in[20];
  float* y = (float*)d_out;

  short* wimg = (short*)d_ws;                          // 176 KB frag images
  float* bu0 = (float*)((char*)d_ws + 176 * 1024);     // 256 B
  float* xlastT = (float*)((char*)d_ws + 180 * 1024);  // 64 x 38400 f32

  k0_prep<<<dim3(45), dim3(256), 0, stream>>>(W_embed, g1, beta1, Lre, Lim,
                                              Bre, Bim, Cre, Cim, lstep,
                                              W_enc, W_dec, W_out, wimg, bu0);
  k1_fused<<<dim3(600), dim3(256), 0, stream>>>(x, wimg, bu0, Lre, Lim, lstep,
                                                g1, beta1, b_embed, Dv, g2,
                                                beta2, xlastT);
  k2_head<<<dim3(2400), dim3(256), 0, stream>>>(xlastT, wimg + 48 * 512, g3,
                                                beta3, b_out, y);
}

// Round 4
// 327.765 us; speedup vs baseline: 1.3500x; 1.0442x over previous
//
#include <hip/hip_runtime.h>
#include <math.h>

// ---------------------------------------------------------------------------
// TemporalSSMPatchwise: b=8,t=15,H=480,W=640, PS=8 -> hp=60,wp=80, n=4800
// d=64, P=32, pp=64.  N_seq = 38400.
// Transpose-free dataflow: weights are MFMA A-operands (pre-permuted rows),
// activations are B-operands.  With row-perm chan(nt,qd,r) =
// (nt>>1)*32 + qd*8 + (nt&1)*4 + r, the D-output register layout of one
// matmul IS the B-operand layout of the next (k-slot = kt*32+qd*8+j,
// identity on channel index).  No transpose, LN = 2 shfl_xor.
// MFMA 16x16x32 bf16: A[m=lane&15][k=qd*8+j], B[k=qd*8+j][n=lane&15],
// D: col=lane&15, row=qd*4+reg (m89/m91-verified).
//
// v4: k2 fused into k1's epilogue.  After the final MFMA the wave holds all
// 64 channels of its 16 seqs in B-operand layout, so LN3 = 2 shfl_xor and
// the W_out GEMM streams its 128 A-fragments (128KB) straight from global
// (L2-resident; 1KB dense per frag read) -- no LDS, no xlastT roundtrip,
// no second weight staging, one less kernel.  y stored with k2's coalesced
// pixel-shuffle mapping (contiguous 512B per row per wave).
// x-ingest (v3): dense cooperative global->LDS via global_load_lds width=16,
// linear LDS dest + inverse-swizzled source + swizzled ds_read (rule-21),
// 2-phase pipeline with counted vmcnt.  LDS 48KB -> 3 blocks/CU.
// ---------------------------------------------------------------------------

typedef __attribute__((ext_vector_type(8))) short short8;
typedef __attribute__((ext_vector_type(4))) float f32x4;

#define MFMA16(a, b, c) __builtin_amdgcn_mfma_f32_16x16x32_bf16((a), (b), (c), 0, 0, 0)

__device__ __forceinline__ short f2bf(float f) {
  union { float f; unsigned u; } v; v.f = f;
  unsigned r = (v.u + 0x7fffu + ((v.u >> 16) & 1u)) >> 16;  // RNE
  return (short)r;
}
__device__ __forceinline__ float geluf(float x) {
  return 0.5f * x * (1.0f + erff(x * 0.70710678118654752f));
}
// pack two C-layout f32x4 tiles (2kt, 2kt+1) into one bf16 B-operand frag
__device__ __forceinline__ short8 packfrag(const f32x4& a, const f32x4& b) {
  short8 o;
  o[0] = f2bf(a[0]); o[1] = f2bf(a[1]); o[2] = f2bf(a[2]); o[3] = f2bf(a[3]);
  o[4] = f2bf(b[0]); o[5] = f2bf(b[1]); o[6] = f2bf(b[2]); o[7] = f2bf(b[3]);
  return o;
}
// weight-row permutation: A-row a = i*16+m  ->  actual channel
__device__ __forceinline__ int ecmap(int i, int m) {
  return (i >> 1) * 32 + (m >> 2) * 8 + (i & 1) * 4 + (m & 3);
}
// Stage-buffer swizzle: involution on byte bits [6:4] keyed by bits
// {7,8,11,12,13} (untouched).  Spreads the per-lane fragment ds_read_b128
// across banks.  Involution => LDS[L] := data[swz(L)] gives
// LDS[swz(b)] == data[b]: linear global_load_lds dest + swizzled source
// + swizzled read is self-consistent (rule 21).
__device__ __forceinline__ int swz(int b) {
  return b ^ (((b >> 2) ^ (b >> 6)) & 0x60) ^ (((b >> 3) ^ (b >> 9)) & 0x10);
}
__device__ __forceinline__ void bbar_factors(const float* Lre, const float* Lim,
                                             const float* lstep, int p,
                                             float& fre, float& fim) {
  float st = expf(lstep[p]);
  float lr = Lre[p], li = Lim[p];
  float er = expf(lr * st);
  float lbr = er * cosf(li * st), lbi = er * sinf(li * st);
  float u = lbr - 1.0f, v = lbi;
  float den = lr * lr + li * li;
  fre = (u * lr + v * li) / den;
  fim = (v * lr - u * li) / den;
}

// ---------------------------------------------------------------------------
// K0: pack 176 A-operand fragments (1 KB each) + bu0.
// ids: 0..7 W_embed | 8..15 Bbar'(g1-folded) | 16..23 Cc2(mask-folded)
//      24..39 W_enc | 40..47 W_dec | 48..175 W_out (natural rows)
// frag(i,kt) value[j] at lane(qd,m): A[i*16+m][k=kt*32+qd*8+j]
// ---------------------------------------------------------------------------
__global__ __launch_bounds__(256) void k0_prep(
    const float* __restrict__ W_embed, const float* __restrict__ g1,
    const float* __restrict__ be1, const float* __restrict__ Lre,
    const float* __restrict__ Lim, const float* __restrict__ Bre,
    const float* __restrict__ Bim, const float* __restrict__ Cre,
    const float* __restrict__ Cim, const float* __restrict__ lstep,
    const float* __restrict__ W_enc, const float* __restrict__ W_dec,
    const float* __restrict__ W_out, short* __restrict__ wimg,
    float* __restrict__ bu0) {
  const int bid = blockIdx.x;
  if (bid == 44) {  // bu0[q] = sum_d beta1[d] * Bbar_comp[p][d]
    int q = threadIdx.x;
    if (q < 64) {
      int c = q >> 5, p = q & 31;
      float fre, fim; bbar_factors(Lre, Lim, lstep, p, fre, fim);
      float s = 0.f;
      for (int d = 0; d < 64; ++d) {
        float br = Bre[p * 64 + d], bi = Bim[p * 64 + d];
        float val = c ? (fre * bi + fim * br) : (fre * br - fim * bi);
        s += be1[d] * val;
      }
      bu0[q] = s;
    }
    return;
  }
  const int w = threadIdx.x >> 6, lane = threadIdx.x & 63;
  const int m = lane & 15, qd = lane >> 4;
  const int f = bid * 4 + w;
  short v[8];
  if (f < 8) {
    int i = f >> 1, kt = f & 1, chan = ecmap(i, m), k0 = kt * 32 + qd * 8;
#pragma unroll
    for (int j = 0; j < 8; ++j) v[j] = f2bf(W_embed[chan * 64 + k0 + j]);
  } else if (f < 16) {
    int fi = f - 8, i = fi >> 1, kt = fi & 1;
    int comp = i & 1, p = (i >> 1) * 16 + m, d0 = kt * 32 + qd * 8;
    float fre, fim; bbar_factors(Lre, Lim, lstep, p, fre, fim);
#pragma unroll
    for (int j = 0; j < 8; ++j) {
      int d = d0 + j;
      float br = Bre[p * 64 + d], bi = Bim[p * 64 + d];
      float val = comp ? (fre * bi + fim * br) : (fre * br - fim * bi);
      v[j] = f2bf(g1[d] * val);
    }
  } else if (f < 24) {
    int fi = f - 16, i = fi >> 1, kt = fi & 1, chan = ecmap(i, m);
#pragma unroll
    for (int j = 0; j < 8; ++j) {
      int comp = j >> 2, p = kt * 16 + qd * 4 + (j & 3);
      float stp = expf(lstep[p]);
      float fr = stp * fabsf(Lim[p]) * (1.0f / 6.28318530717958648f);
      float msk = (fr < 0.5f) ? 1.f : 0.f;
      float val = comp ? -Cim[chan * 32 + p] * msk : Cre[chan * 32 + p] * msk;
      v[j] = f2bf(val);
    }
  } else if (f < 40) {
    int fi = f - 24, i = fi >> 1, kt = fi & 1;
    int row = (i < 4) ? ecmap(i, m) : 64 + ecmap(i - 4, m);
#pragma unroll
    for (int j = 0; j < 8; ++j) v[j] = f2bf(W_enc[row * 64 + kt * 32 + qd * 8 + j]);
  } else if (f < 48) {
    int fi = f - 40, i = fi >> 1, kt = fi & 1, row = ecmap(i, m);
#pragma unroll
    for (int j = 0; j < 8; ++j) v[j] = f2bf(W_dec[row * 64 + kt * 32 + qd * 8 + j]);
  } else {
    int fi = f - 48, i = fi >> 1, kt = fi & 1, row = i * 16 + m;  // natural
#pragma unroll
    for (int j = 0; j < 8; ++j) v[j] = f2bf(W_out[row * 64 + kt * 32 + qd * 8 + j]);
  }
  short8 sv;
#pragma unroll
  for (int j = 0; j < 8; ++j) sv[j] = v[j];
  *(short8*)&wimg[(f * 64 + lane) * 8] = sv;
}

// ---------------------------------------------------------------------------
// K1: embed -> LN1 -> Bu -> scan -> head(MLP) -> LN3 -> W_out -> y.
// 256 thr = 4 waves, 16 seqs/wave, grid 600.  LDS: [0,16K) scan frags,
// [16K,48K) x stage dbuf (head frags swapped in after scan) -> 48KB.
// ---------------------------------------------------------------------------
__global__ __launch_bounds__(256) void k1_fused(
    const float* __restrict__ x, const short* __restrict__ wimg_g,
    const float* __restrict__ bu0_g, const float* __restrict__ Lre,
    const float* __restrict__ Lim, const float* __restrict__ lstep,
    const float* __restrict__ g1, const float* __restrict__ be1,
    const float* __restrict__ bemb, const float* __restrict__ Dv,
    const float* __restrict__ g2, const float* __restrict__ be2,
    const float* __restrict__ g3, const float* __restrict__ be3,
    const float* __restrict__ b_out, float* __restrict__ y) {
  __shared__ __align__(16) char smem[49152];
#define WF(id) (*(const short8*)(smem + (id) * 1024 + lane * 16))

  const int tid = threadIdx.x;
  const int wv = tid >> 6, lane = tid & 63;
  const int s = lane & 15, qd = lane >> 4;

  // ---- scan-weight loads (16KB, frags 0..15) into regs (issued first) ----
  float4 wreg[4];
  {
    const float4* src = (const float4*)wimg_g;
#pragma unroll
    for (int j = 0; j < 4; ++j) wreg[j] = src[j * 256 + tid];
  }

  // ---- per-lane constants (all global reads before staging starts) ----
  int cb[4];
  f32x4 bec[4], bu0c[4];
#pragma unroll
  for (int nt = 0; nt < 4; ++nt) {
    cb[nt] = (nt >> 1) * 32 + qd * 8 + (nt & 1) * 4;
    bec[nt] = *(const f32x4*)(bemb + cb[nt]);
    bu0c[nt] = *(const f32x4*)(bu0_g + (nt & 1) * 32 + (nt >> 1) * 16 + qd * 4);
  }
  f32x4 lbr[2], lbi[2];
#pragma unroll
  for (int k = 0; k < 2; ++k)
#pragma unroll
    for (int r = 0; r < 4; ++r) {
      int p = k * 16 + qd * 4 + r;
      float st = expf(lstep[p]);
      float er = expf(Lre[p] * st);
      lbr[k][r] = er * cosf(Lim[p] * st);
      lbi[k][r] = er * sinf(Lim[p] * st);
    }

  // ---- staging geometry ----
  // Logical byte b of a 16KB tile: bits[3:0] within-16B, bit4=h (8B half),
  // bits[10:5]=p (patch in block), bits[13:11]=r (row in patch).
  // Wave wv, instr j writes LDS linear bytes L=(wv*4+j)*1024 + lane*16;
  // source for that lane is logical chunk swz(L) (involution).
  int off[4];
#pragma unroll
  for (int j = 0; j < 4; ++j) {
    int L = (wv * 4 + j) * 1024 + lane * 16;
    int b = swz(L);
    int c = b >> 4;
    int r = c >> 7, p = (c >> 1) & 63, h = c & 1;
    int seq = blockIdx.x * 64 + p;
    int b_i = seq / 4800, pr = seq % 4800;
    int ph = pr / 80, pw = pr % 80;
    off[j] = ((b_i * 15) * 480 + ph * 8 + r) * 640 + pw * 8 + h * 4;  // floats
  }
  // per-lane fragment read addresses (within a stage buffer), swizzled
  int rb[4];
#pragma unroll
  for (int kt = 0; kt < 2; ++kt)
#pragma unroll
    for (int h = 0; h < 2; ++h) {
      int b = (kt * 4 + qd) * 2048 + (wv * 16 + s) * 32 + h * 16;
      rb[kt * 2 + h] = swz(b);
    }

#define STAGE(bufofs, tt)                                                     \
  {                                                                           \
    const float* gsrc = x + (tt) * 307200;                                    \
    char* lb = smem + (bufofs) + wv * 4096;                                   \
    _Pragma("unroll") for (int j = 0; j < 4; ++j)                             \
        __builtin_amdgcn_global_load_lds(                                     \
            (const __attribute__((address_space(1))) void*)(gsrc + off[j]),   \
            (__attribute__((address_space(3))) void*)(lb + j * 1024),         \
            16, 0, 0);                                                        \
  }

  const int sbase = (blockIdx.x * 4 + wv) * 16;

  // ---- prologue: stage t=0 and t=1 (async), weights -> LDS, full drain ----
  STAGE(16384, 0);
  STAGE(32768, 1);
  {
    float4* wdst = (float4*)smem;
#pragma unroll
    for (int j = 0; j < 4; ++j) wdst[j * 256 + tid] = wreg[j];
  }
  // vmcnt(0): order of the two prologue STAGEs is not guaranteed by the
  // compiler, so a counted wait here could leave t=0 loads in flight.
  asm volatile("s_waitcnt vmcnt(0) lgkmcnt(0)" ::: "memory");
  __builtin_amdgcn_s_barrier();

  const f32x4 zf = {0.f, 0.f, 0.f, 0.f};
  f32x4 state[4] = {zf, zf, zf, zf};
  f32x4 xh[4];

  for (int t = 0; t < 15; ++t) {
    // read this tile's fragments from buf[t&1]
    const char* bufr = smem + 16384 + ((t & 1) << 14);
    f32x4 vcur[4];
#pragma unroll
    for (int q = 0; q < 4; ++q) vcur[q] = *(const f32x4*)(bufr + rb[q]);
    asm volatile("s_waitcnt lgkmcnt(0)" ::: "memory");  // reads retired
    __builtin_amdgcn_s_barrier();  // B1: all waves done reading buf[t&1]
    if (t < 13) STAGE(16384 + ((t & 1) << 14), t + 2);  // overwrite, async

    short8 pa0 = packfrag(vcur[0], vcur[1]);
    short8 pa1 = packfrag(vcur[2], vcur[3]);
    f32x4 c1[4];
#pragma unroll
    for (int i = 0; i < 4; ++i) {
      f32x4 acc = MFMA16(WF(i * 2), pa0, zf);
      acc = MFMA16(WF(i * 2 + 1), pa1, acc);
      c1[i] = acc + bec[i];
    }
    float sm = 0.f, sq = 0.f;
#pragma unroll
    for (int nt = 0; nt < 4; ++nt)
#pragma unroll
      for (int i = 0; i < 4; ++i) { sm += c1[nt][i]; sq += c1[nt][i] * c1[nt][i]; }
    sm += __shfl_xor(sm, 16); sq += __shfl_xor(sq, 16);
    sm += __shfl_xor(sm, 32); sq += __shfl_xor(sq, 32);
    float mean = sm * 0.015625f;
    float rstd = rsqrtf(sq * 0.015625f - mean * mean + 1e-5f);
#pragma unroll
    for (int nt = 0; nt < 4; ++nt) xh[nt] = (c1[nt] - mean) * rstd;
    short8 xa0 = packfrag(xh[0], xh[1]);
    short8 xa1 = packfrag(xh[2], xh[3]);
#pragma unroll
    for (int k = 0; k < 2; ++k) {
      f32x4 re = state[2 * k], im = state[2 * k + 1];
      state[2 * k]     = lbr[k] * re - lbi[k] * im + bu0c[2 * k];
      state[2 * k + 1] = lbr[k] * im + lbi[k] * re + bu0c[2 * k + 1];
    }
#pragma unroll
    for (int i = 0; i < 4; ++i) {
      state[i] = MFMA16(WF(8 + i * 2), xa0, state[i]);
      state[i] = MFMA16(WF(8 + i * 2 + 1), xa1, state[i]);
    }

    // before next iter reads buf[(t+1)&1]: own stage(t+1) loads done, then
    // barrier => all waves' stage(t+1) done.  Counted: stage(t+2)'s 4 loads
    // stay in flight (never drain to 0 in steady state).  Only one STAGE per
    // fence window, so the count is order-safe here.
    if (t < 14) {
      if (t < 13) asm volatile("s_waitcnt vmcnt(4)" ::: "memory");
      else        asm volatile("s_waitcnt vmcnt(0)" ::: "memory");
      __builtin_amdgcn_s_barrier();  // B2
    }
  }
#undef STAGE

  // ---- swap head frags (16..47, 32KB) into the stage-buffer space ----
  __syncthreads();
  {
    float4 hf[8];
    const float4* src = (const float4*)(wimg_g + 16 * 512);
#pragma unroll
    for (int j = 0; j < 8; ++j) hf[j] = src[j * 256 + tid];
    float4* dst = (float4*)(smem + 16384);
#pragma unroll
    for (int j = 0; j < 8; ++j) dst[j * 256 + tid] = hf[j];
  }
  __syncthreads();

  // ---- head at t = 14 ----
  f32x4 g1c[4], b1c[4], Dc[4], g2c[4], b2c[4];
#pragma unroll
  for (int nt = 0; nt < 4; ++nt) {
    g1c[nt] = *(const f32x4*)(g1 + cb[nt]);
    b1c[nt] = *(const f32x4*)(be1 + cb[nt]);
    Dc[nt] = *(const f32x4*)(Dv + cb[nt]);
    g2c[nt] = *(const f32x4*)(g2 + cb[nt]);
    b2c[nt] = *(const f32x4*)(be2 + cb[nt]);
  }
  f32x4 fxl[4];
#pragma unroll
  for (int nt = 0; nt < 4; ++nt) fxl[nt] = xh[nt] * g1c[nt] + b1c[nt];

  short8 xsa0 = packfrag(state[0], state[1]);
  short8 xsa1 = packfrag(state[2], state[3]);
  f32x4 xbv[4];
#pragma unroll
  for (int i = 0; i < 4; ++i) {
    f32x4 acc = fxl[i] * Dc[i];
    acc = MFMA16(WF(16 + i * 2), xsa0, acc);
    acc = MFMA16(WF(16 + i * 2 + 1), xsa1, acc);
#pragma unroll
    for (int r = 0; r < 4; ++r) xbv[i][r] = geluf(acc[r]) + fxl[i][r];
  }
  float sm2 = 0.f, sq2 = 0.f;
#pragma unroll
  for (int nt = 0; nt < 4; ++nt)
#pragma unroll
    for (int i = 0; i < 4; ++i) { sm2 += xbv[nt][i]; sq2 += xbv[nt][i] * xbv[nt][i]; }
  sm2 += __shfl_xor(sm2, 16); sq2 += __shfl_xor(sq2, 16);
  sm2 += __shfl_xor(sm2, 32); sq2 += __shfl_xor(sq2, 32);
  float mean2 = sm2 * 0.015625f;
  float rstd2 = rsqrtf(sq2 * 0.015625f - mean2 * mean2 + 1e-5f);
  f32x4 fx2[4];
#pragma unroll
  for (int nt = 0; nt < 4; ++nt)
    fx2[nt] = (xbv[nt] - mean2) * rstd2 * g2c[nt] + b2c[nt];

  short8 fa0 = packfrag(fx2[0], fx2[1]);
  short8 fa1 = packfrag(fx2[2], fx2[3]);
  f32x4 e[8];
#pragma unroll
  for (int i = 0; i < 8; ++i) {
    f32x4 acc = MFMA16(WF(24 + i * 2), fa0, zf);
    e[i] = MFMA16(WF(24 + i * 2 + 1), fa1, acc);
  }
  f32x4 hv[4];
#pragma unroll
  for (int nt = 0; nt < 4; ++nt)
#pragma unroll
    for (int i = 0; i < 4; ++i) hv[nt][i] = e[nt][i] * geluf(e[nt + 4][i]);

  short8 ha0 = packfrag(hv[0], hv[1]);
  short8 ha1 = packfrag(hv[2], hv[3]);
  f32x4 xo[4];
#pragma unroll
  for (int i = 0; i < 4; ++i) {
    f32x4 acc = fx2[i];
    acc = MFMA16(WF(40 + i * 2), ha0, acc);
    xo[i] = MFMA16(WF(40 + i * 2 + 1), ha1, acc);
  }

  // ---- fused k2: LN3 + W_out GEMM + pixel-shuffle store ----
  // xo[nt][r] holds channel cb[nt]+r of seq sbase+s: already B-operand layout.
  float sm3 = 0.f, sq3 = 0.f;
#pragma unroll
  for (int nt = 0; nt < 4; ++nt)
#pragma unroll
    for (int i = 0; i < 4; ++i) { sm3 += xo[nt][i]; sq3 += xo[nt][i] * xo[nt][i]; }
  sm3 += __shfl_xor(sm3, 16); sq3 += __shfl_xor(sq3, 16);
  sm3 += __shfl_xor(sm3, 32); sq3 += __shfl_xor(sq3, 32);
  float mean3 = sm3 * 0.015625f;
  float rstd3 = rsqrtf(sq3 * 0.015625f - mean3 * mean3 + 1e-5f);
  f32x4 z[4];
#pragma unroll
  for (int nt = 0; nt < 4; ++nt) {
    f32x4 g3c = *(const f32x4*)(g3 + cb[nt]);
    f32x4 b3c = *(const f32x4*)(be3 + cb[nt]);
    z[nt] = (xo[nt] - mean3) * rstd3 * g3c + b3c;
  }
  short8 za = packfrag(z[0], z[1]);
  short8 zb = packfrag(z[2], z[3]);

  const int seq = sbase + s;
  const int bi2 = seq / 4800, prr = seq % 4800;
  const int phh = prr / 80, pww = prr % 80;
  const int obase = (bi2 * 16 * 480 + phh * 8) * 640 + pww * 8;
  const short* wob = wimg_g + 48 * 512;  // W_out frag images (128KB, L2-hot)

#pragma unroll 4
  for (int ntg = 0; ntg < 64; ++ntg) {
    short8 a0 = *(const short8*)&wob[(ntg * 2 + 0) * 512 + lane * 8];
    short8 a1 = *(const short8*)&wob[(ntg * 2 + 1) * 512 + lane * 8];
    int o0 = ntg * 16 + qd * 4;
    f32x4 acc = *(const f32x4*)(b_out + o0);
    acc = MFMA16(a0, za, acc);
    acc = MFMA16(a1, zb, acc);
    int c = o0 >> 6, pi = (o0 >> 3) & 7, pj = o0 & 7;
    *(f32x4*)&y[obase + c * 307200 + pi * 640 + pj] = acc;
  }
#undef WF
}

// ---------------------------------------------------------------------------
extern "C" void kernel_launch(void* const* d_in, const int* in_sizes, int n_in,
                              void* d_out, int out_size, void* d_ws, size_t ws_size,
                              hipStream_t stream) {
  const float* x       = (const float*)d_in[0];
  const float* W_embed = (const float*)d_in[1];
  const float* b_embed = (const float*)d_in[2];
  const float* g1      = (const float*)d_in[3];
  const float* beta1   = (const float*)d_in[4];
  const float* Lre     = (const float*)d_in[5];
  const float* Lim     = (const float*)d_in[6];
  const float* Bre     = (const float*)d_in[7];
  const float* Bim     = (const float*)d_in[8];
  const float* Cre     = (const float*)d_in[9];
  const float* Cim     = (const float*)d_in[10];
  const float* Dv      = (const float*)d_in[11];
  const float* lstep   = (const float*)d_in[12];
  const float* g2      = (const float*)d_in[13];
  const float* beta2   = (const float*)d_in[14];
  const float* W_enc   = (const float*)d_in[15];
  const float* W_dec   = (const float*)d_in[16];
  const float* g3      = (const float*)d_in[17];
  const float* beta3   = (const float*)d_in[18];
  const float* W_out   = (const float*)d_in[19];
  const float* b_out   = (const float*)d_in[20];
  float* y = (float*)d_out;

  short* wimg = (short*)d_ws;                          // 176 KB frag images
  float* bu0 = (float*)((char*)d_ws + 176 * 1024);     // 256 B

  k0_prep<<<dim3(45), dim3(256), 0, stream>>>(W_embed, g1, beta1, Lre, Lim,
                                              Bre, Bim, Cre, Cim, lstep,
                                              W_enc, W_dec, W_out, wimg, bu0);
  k1_fused<<<dim3(600), dim3(256), 0, stream>>>(x, wimg, bu0, Lre, Lim, lstep,
                                                g1, beta1, b_embed, Dv, g2,
                                                beta2, g3, beta3, b_out, y);
}

// Round 5
// 325.513 us; speedup vs baseline: 1.3594x; 1.0069x over previous
//
#include <hip/hip_runtime.h>
#include <math.h>

// ---------------------------------------------------------------------------
// TemporalSSMPatchwise: b=8,t=15,H=480,W=640, PS=8 -> hp=60,wp=80, n=4800
// d=64, P=32, pp=64.  N_seq = 38400.
// Transpose-free dataflow: weights are MFMA A-operands (pre-permuted rows),
// activations are B-operands.  With row-perm chan(nt,qd,r) =
// (nt>>1)*32 + qd*8 + (nt&1)*4 + r, the D-output register layout of one
// matmul IS the B-operand layout of the next (k-slot = kt*32+qd*8+j,
// identity on channel index).  No transpose, LN = 2 shfl_xor.
// MFMA 16x16x32 bf16: A[m=lane&15][k=qd*8+j], B[k=qd*8+j][n=lane&15],
// D: col=lane&15, row=qd*4+reg (m89/m91-verified).
//
// v5: BARRIER-FREE scan.  v4's block-cooperative staging kept all 600 blocks
// in 2-barrier lockstep; waves idled ~70% of each 5.2us period while the
// in-phase 9.8MB/t chip burst drained (scan ran at 1.9 TB/s vs 6.3 achievable).
// Now each wave stages its OWN 4KB/t tile (16 patches x 8 rows = 8 dense
// 512B runs; 4 global_load_lds width-16 per t) into a private 2x4KB LDS
// double-buffer, ordered only by its own counted vmcnt(4)/lgkmcnt(0).
// Zero s_barrier in the t-loop; ~9.4 waves/CU free-run against HBM.
// LDS: 16KB weights (read-only after prologue sync) + 4x8KB wave buffers
// = 48KB -> 3 blocks/CU.  Epilogue (fused k2: LN3 + W_out GEMM + pixel-
// shuffle y store, W_out A-frags streamed from global/L2) unchanged from v4.
// ---------------------------------------------------------------------------

typedef __attribute__((ext_vector_type(8))) short short8;
typedef __attribute__((ext_vector_type(4))) float f32x4;

#define MFMA16(a, b, c) __builtin_amdgcn_mfma_f32_16x16x32_bf16((a), (b), (c), 0, 0, 0)

__device__ __forceinline__ short f2bf(float f) {
  union { float f; unsigned u; } v; v.f = f;
  unsigned r = (v.u + 0x7fffu + ((v.u >> 16) & 1u)) >> 16;  // RNE
  return (short)r;
}
__device__ __forceinline__ float geluf(float x) {
  return 0.5f * x * (1.0f + erff(x * 0.70710678118654752f));
}
// pack two C-layout f32x4 tiles (2kt, 2kt+1) into one bf16 B-operand frag
__device__ __forceinline__ short8 packfrag(const f32x4& a, const f32x4& b) {
  short8 o;
  o[0] = f2bf(a[0]); o[1] = f2bf(a[1]); o[2] = f2bf(a[2]); o[3] = f2bf(a[3]);
  o[4] = f2bf(b[0]); o[5] = f2bf(b[1]); o[6] = f2bf(b[2]); o[7] = f2bf(b[3]);
  return o;
}
// weight-row permutation: A-row a = i*16+m  ->  actual channel
__device__ __forceinline__ int ecmap(int i, int m) {
  return (i >> 1) * 32 + (m >> 2) * 8 + (i & 1) * 4 + (m & 3);
}
__device__ __forceinline__ void bbar_factors(const float* Lre, const float* Lim,
                                             const float* lstep, int p,
                                             float& fre, float& fim) {
  float st = expf(lstep[p]);
  float lr = Lre[p], li = Lim[p];
  float er = expf(lr * st);
  float lbr = er * cosf(li * st), lbi = er * sinf(li * st);
  float u = lbr - 1.0f, v = lbi;
  float den = lr * lr + li * li;
  fre = (u * lr + v * li) / den;
  fim = (v * lr - u * li) / den;
}

// ---------------------------------------------------------------------------
// K0: pack 176 A-operand fragments (1 KB each) + bu0.
// ids: 0..7 W_embed | 8..15 Bbar'(g1-folded) | 16..23 Cc2(mask-folded)
//      24..39 W_enc | 40..47 W_dec | 48..175 W_out (natural rows)
// frag(i,kt) value[j] at lane(qd,m): A[i*16+m][k=kt*32+qd*8+j]
// ---------------------------------------------------------------------------
__global__ __launch_bounds__(256) void k0_prep(
    const float* __restrict__ W_embed, const float* __restrict__ g1,
    const float* __restrict__ be1, const float* __restrict__ Lre,
    const float* __restrict__ Lim, const float* __restrict__ Bre,
    const float* __restrict__ Bim, const float* __restrict__ Cre,
    const float* __restrict__ Cim, const float* __restrict__ lstep,
    const float* __restrict__ W_enc, const float* __restrict__ W_dec,
    const float* __restrict__ W_out, short* __restrict__ wimg,
    float* __restrict__ bu0) {
  const int bid = blockIdx.x;
  if (bid == 44) {  // bu0[q] = sum_d beta1[d] * Bbar_comp[p][d]
    int q = threadIdx.x;
    if (q < 64) {
      int c = q >> 5, p = q & 31;
      float fre, fim; bbar_factors(Lre, Lim, lstep, p, fre, fim);
      float s = 0.f;
      for (int d = 0; d < 64; ++d) {
        float br = Bre[p * 64 + d], bi = Bim[p * 64 + d];
        float val = c ? (fre * bi + fim * br) : (fre * br - fim * bi);
        s += be1[d] * val;
      }
      bu0[q] = s;
    }
    return;
  }
  const int w = threadIdx.x >> 6, lane = threadIdx.x & 63;
  const int m = lane & 15, qd = lane >> 4;
  const int f = bid * 4 + w;
  short v[8];
  if (f < 8) {
    int i = f >> 1, kt = f & 1, chan = ecmap(i, m), k0 = kt * 32 + qd * 8;
#pragma unroll
    for (int j = 0; j < 8; ++j) v[j] = f2bf(W_embed[chan * 64 + k0 + j]);
  } else if (f < 16) {
    int fi = f - 8, i = fi >> 1, kt = fi & 1;
    int comp = i & 1, p = (i >> 1) * 16 + m, d0 = kt * 32 + qd * 8;
    float fre, fim; bbar_factors(Lre, Lim, lstep, p, fre, fim);
#pragma unroll
    for (int j = 0; j < 8; ++j) {
      int d = d0 + j;
      float br = Bre[p * 64 + d], bi = Bim[p * 64 + d];
      float val = comp ? (fre * bi + fim * br) : (fre * br - fim * bi);
      v[j] = f2bf(g1[d] * val);
    }
  } else if (f < 24) {
    int fi = f - 16, i = fi >> 1, kt = fi & 1, chan = ecmap(i, m);
#pragma unroll
    for (int j = 0; j < 8; ++j) {
      int comp = j >> 2, p = kt * 16 + qd * 4 + (j & 3);
      float stp = expf(lstep[p]);
      float fr = stp * fabsf(Lim[p]) * (1.0f / 6.28318530717958648f);
      float msk = (fr < 0.5f) ? 1.f : 0.f;
      float val = comp ? -Cim[chan * 32 + p] * msk : Cre[chan * 32 + p] * msk;
      v[j] = f2bf(val);
    }
  } else if (f < 40) {
    int fi = f - 24, i = fi >> 1, kt = fi & 1;
    int row = (i < 4) ? ecmap(i, m) : 64 + ecmap(i - 4, m);
#pragma unroll
    for (int j = 0; j < 8; ++j) v[j] = f2bf(W_enc[row * 64 + kt * 32 + qd * 8 + j]);
  } else if (f < 48) {
    int fi = f - 40, i = fi >> 1, kt = fi & 1, row = ecmap(i, m);
#pragma unroll
    for (int j = 0; j < 8; ++j) v[j] = f2bf(W_dec[row * 64 + kt * 32 + qd * 8 + j]);
  } else {
    int fi = f - 48, i = fi >> 1, kt = fi & 1, row = i * 16 + m;  // natural
#pragma unroll
    for (int j = 0; j < 8; ++j) v[j] = f2bf(W_out[row * 64 + kt * 32 + qd * 8 + j]);
  }
  short8 sv;
#pragma unroll
  for (int j = 0; j < 8; ++j) sv[j] = v[j];
  *(short8*)&wimg[(f * 64 + lane) * 8] = sv;
}

// ---------------------------------------------------------------------------
// K1: embed -> LN1 -> Bu -> scan -> head(MLP) -> LN3 -> W_out -> y.
// 256 thr = 4 waves, 16 seqs/wave, grid 600.  LDS: [0,16K) scan frags,
// [16K,48K) per-wave 8KB stage dbufs (head frags swapped in after scan).
// ---------------------------------------------------------------------------
__global__ __launch_bounds__(256) void k1_fused(
    const float* __restrict__ x, const short* __restrict__ wimg_g,
    const float* __restrict__ bu0_g, const float* __restrict__ Lre,
    const float* __restrict__ Lim, const float* __restrict__ lstep,
    const float* __restrict__ g1, const float* __restrict__ be1,
    const float* __restrict__ bemb, const float* __restrict__ Dv,
    const float* __restrict__ g2, const float* __restrict__ be2,
    const float* __restrict__ g3, const float* __restrict__ be3,
    const float* __restrict__ b_out, float* __restrict__ y) {
  __shared__ __align__(16) char smem[49152];
#define WF(id) (*(const short8*)(smem + (id) * 1024 + lane * 16))

  const int tid = threadIdx.x;
  const int wv = tid >> 6, lane = tid & 63;
  const int s = lane & 15, qd = lane >> 4;

  // ---- scan-weight loads (16KB, frags 0..15) into regs (issued first) ----
  float4 wreg[4];
  {
    const float4* src = (const float4*)wimg_g;
#pragma unroll
    for (int j = 0; j < 4; ++j) wreg[j] = src[j * 256 + tid];
  }

  // ---- per-lane constants (all global reads before staging starts) ----
  int cb[4];
  f32x4 bec[4], bu0c[4];
#pragma unroll
  for (int nt = 0; nt < 4; ++nt) {
    cb[nt] = (nt >> 1) * 32 + qd * 8 + (nt & 1) * 4;
    bec[nt] = *(const f32x4*)(bemb + cb[nt]);
    bu0c[nt] = *(const f32x4*)(bu0_g + (nt & 1) * 32 + (nt >> 1) * 16 + qd * 4);
  }
  f32x4 lbr[2], lbi[2];
#pragma unroll
  for (int k = 0; k < 2; ++k)
#pragma unroll
    for (int r = 0; r < 4; ++r) {
      int p = k * 16 + qd * 4 + r;
      float st = expf(lstep[p]);
      float er = expf(Lre[p] * st);
      lbr[k][r] = er * cosf(Lim[p] * st);
      lbi[k][r] = er * sinf(Lim[p] * st);
    }

  // ---- per-wave staging geometry ----
  // Wave tile = 16 patches x 8 rows x 32B = 4KB; logical byte of tile:
  // [3:0] within-16B | [4] h (8B half) | [8:5] s (patch) | [11:9] r (row).
  // Linear LDS layout == global dense order per row: instr j, lane l writes
  // LDS byte L = j*1024 + l*16 and reads global row r = j*2 + (l>>5),
  // within-row byte (l&31)*16  -> two contiguous 512B runs per instruction.
  const int sbase = (blockIdx.x * 4 + wv) * 16;
  const int b_i = sbase / 4800;
  const int prw = sbase % 4800;
  const int phw = prw / 80, pw0 = prw % 80;
  int offw[4];
#pragma unroll
  for (int j = 0; j < 4; ++j) {
    int r = j * 2 + (lane >> 5);
    offw[j] = ((b_i * 15) * 480 + phw * 8 + r) * 640 + pw0 * 8 + (lane & 31) * 4;
  }
  // fragment read offsets within the wave's 4KB tile: row kt*4+qd, patch s,
  // half h  ->  r*512 + s*32 + h*16
  int rb[4];
#pragma unroll
  for (int kt = 0; kt < 2; ++kt)
#pragma unroll
    for (int h = 0; h < 2; ++h)
      rb[kt * 2 + h] = (kt * 4 + qd) * 512 + s * 32 + h * 16;

  char* const wbuf = smem + 16384 + wv * 8192;  // this wave's 2x4KB dbuf

#define STAGEW(tsel, tt)                                                      \
  {                                                                           \
    const float* gsrc = x + (tt) * 307200;                                    \
    char* lb = wbuf + (tsel) * 4096;                                          \
    _Pragma("unroll") for (int j = 0; j < 4; ++j)                             \
        __builtin_amdgcn_global_load_lds(                                     \
            (const __attribute__((address_space(1))) void*)(gsrc + offw[j]),  \
            (__attribute__((address_space(3))) void*)(lb + j * 1024),         \
            16, 0, 0);                                                        \
  }

  // ---- prologue: weights -> LDS, one sync, then per-wave async staging ----
  {
    float4* wdst = (float4*)smem;
#pragma unroll
    for (int j = 0; j < 4; ++j) wdst[j * 256 + tid] = wreg[j];
  }
  __syncthreads();   // weights visible; implicit vmcnt(0) -> counters clean
  STAGEW(0, 0);
  STAGEW(1, 1);

  const f32x4 zf = {0.f, 0.f, 0.f, 0.f};
  f32x4 state[4] = {zf, zf, zf, zf};
  f32x4 xh[4];

  for (int t = 0; t < 15; ++t) {
    // wave-private pipeline: all but the newest 4 loads (= stage(t+1)) done
    // => stage(t) landed.  No block barrier anywhere in this loop.
    if (t < 14) asm volatile("s_waitcnt vmcnt(4)" ::: "memory");
    else        asm volatile("s_waitcnt vmcnt(0)" ::: "memory");
    const char* bufr = wbuf + ((t & 1) << 12);
    f32x4 vcur[4];
#pragma unroll
    for (int q = 0; q < 4; ++q) vcur[q] = *(const f32x4*)(bufr + rb[q]);
    asm volatile("s_waitcnt lgkmcnt(0)" ::: "memory");  // own reads retired
    if (t < 13) STAGEW(t & 1, t + 2);  // overwrite own just-read buffer

    short8 pa0 = packfrag(vcur[0], vcur[1]);
    short8 pa1 = packfrag(vcur[2], vcur[3]);
    f32x4 c1[4];
#pragma unroll
    for (int i = 0; i < 4; ++i) {
      f32x4 acc = MFMA16(WF(i * 2), pa0, zf);
      acc = MFMA16(WF(i * 2 + 1), pa1, acc);
      c1[i] = acc + bec[i];
    }
    float sm = 0.f, sq = 0.f;
#pragma unroll
    for (int nt = 0; nt < 4; ++nt)
#pragma unroll
      for (int i = 0; i < 4; ++i) { sm += c1[nt][i]; sq += c1[nt][i] * c1[nt][i]; }
    sm += __shfl_xor(sm, 16); sq += __shfl_xor(sq, 16);
    sm += __shfl_xor(sm, 32); sq += __shfl_xor(sq, 32);
    float mean = sm * 0.015625f;
    float rstd = rsqrtf(sq * 0.015625f - mean * mean + 1e-5f);
#pragma unroll
    for (int nt = 0; nt < 4; ++nt) xh[nt] = (c1[nt] - mean) * rstd;
    short8 xa0 = packfrag(xh[0], xh[1]);
    short8 xa1 = packfrag(xh[2], xh[3]);
#pragma unroll
    for (int k = 0; k < 2; ++k) {
      f32x4 re = state[2 * k], im = state[2 * k + 1];
      state[2 * k]     = lbr[k] * re - lbi[k] * im + bu0c[2 * k];
      state[2 * k + 1] = lbr[k] * im + lbi[k] * re + bu0c[2 * k + 1];
    }
#pragma unroll
    for (int i = 0; i < 4; ++i) {
      state[i] = MFMA16(WF(8 + i * 2), xa0, state[i]);
      state[i] = MFMA16(WF(8 + i * 2 + 1), xa1, state[i]);
    }
  }
#undef STAGEW

  // ---- swap head frags (16..47, 32KB) into the stage-buffer space ----
  __syncthreads();  // all waves done with their stage buffers
  {
    float4 hf[8];
    const float4* src = (const float4*)(wimg_g + 16 * 512);
#pragma unroll
    for (int j = 0; j < 8; ++j) hf[j] = src[j * 256 + tid];
    float4* dst = (float4*)(smem + 16384);
#pragma unroll
    for (int j = 0; j < 8; ++j) dst[j * 256 + tid] = hf[j];
  }
  __syncthreads();

  // ---- head at t = 14 ----
  f32x4 g1c[4], b1c[4], Dc[4], g2c[4], b2c[4];
#pragma unroll
  for (int nt = 0; nt < 4; ++nt) {
    g1c[nt] = *(const f32x4*)(g1 + cb[nt]);
    b1c[nt] = *(const f32x4*)(be1 + cb[nt]);
    Dc[nt] = *(const f32x4*)(Dv + cb[nt]);
    g2c[nt] = *(const f32x4*)(g2 + cb[nt]);
    b2c[nt] = *(const f32x4*)(be2 + cb[nt]);
  }
  f32x4 fxl[4];
#pragma unroll
  for (int nt = 0; nt < 4; ++nt) fxl[nt] = xh[nt] * g1c[nt] + b1c[nt];

  short8 xsa0 = packfrag(state[0], state[1]);
  short8 xsa1 = packfrag(state[2], state[3]);
  f32x4 xbv[4];
#pragma unroll
  for (int i = 0; i < 4; ++i) {
    f32x4 acc = fxl[i] * Dc[i];
    acc = MFMA16(WF(16 + i * 2), xsa0, acc);
    acc = MFMA16(WF(16 + i * 2 + 1), xsa1, acc);
#pragma unroll
    for (int r = 0; r < 4; ++r) xbv[i][r] = geluf(acc[r]) + fxl[i][r];
  }
  float sm2 = 0.f, sq2 = 0.f;
#pragma unroll
  for (int nt = 0; nt < 4; ++nt)
#pragma unroll
    for (int i = 0; i < 4; ++i) { sm2 += xbv[nt][i]; sq2 += xbv[nt][i] * xbv[nt][i]; }
  sm2 += __shfl_xor(sm2, 16); sq2 += __shfl_xor(sq2, 16);
  sm2 += __shfl_xor(sm2, 32); sq2 += __shfl_xor(sq2, 32);
  float mean2 = sm2 * 0.015625f;
  float rstd2 = rsqrtf(sq2 * 0.015625f - mean2 * mean2 + 1e-5f);
  f32x4 fx2[4];
#pragma unroll
  for (int nt = 0; nt < 4; ++nt)
    fx2[nt] = (xbv[nt] - mean2) * rstd2 * g2c[nt] + b2c[nt];

  short8 fa0 = packfrag(fx2[0], fx2[1]);
  short8 fa1 = packfrag(fx2[2], fx2[3]);
  f32x4 e[8];
#pragma unroll
  for (int i = 0; i < 8; ++i) {
    f32x4 acc = MFMA16(WF(24 + i * 2), fa0, zf);
    e[i] = MFMA16(WF(24 + i * 2 + 1), fa1, acc);
  }
  f32x4 hv[4];
#pragma unroll
  for (int nt = 0; nt < 4; ++nt)
#pragma unroll
    for (int i = 0; i < 4; ++i) hv[nt][i] = e[nt][i] * geluf(e[nt + 4][i]);

  short8 ha0 = packfrag(hv[0], hv[1]);
  short8 ha1 = packfrag(hv[2], hv[3]);
  f32x4 xo[4];
#pragma unroll
  for (int i = 0; i < 4; ++i) {
    f32x4 acc = fx2[i];
    acc = MFMA16(WF(40 + i * 2), ha0, acc);
    xo[i] = MFMA16(WF(40 + i * 2 + 1), ha1, acc);
  }

  // ---- fused k2: LN3 + W_out GEMM + pixel-shuffle store ----
  // xo[nt][r] holds channel cb[nt]+r of seq sbase+s: already B-operand layout.
  float sm3 = 0.f, sq3 = 0.f;
#pragma unroll
  for (int nt = 0; nt < 4; ++nt)
#pragma unroll
    for (int i = 0; i < 4; ++i) { sm3 += xo[nt][i]; sq3 += xo[nt][i] * xo[nt][i]; }
  sm3 += __shfl_xor(sm3, 16); sq3 += __shfl_xor(sq3, 16);
  sm3 += __shfl_xor(sm3, 32); sq3 += __shfl_xor(sq3, 32);
  float mean3 = sm3 * 0.015625f;
  float rstd3 = rsqrtf(sq3 * 0.015625f - mean3 * mean3 + 1e-5f);
  f32x4 z[4];
#pragma unroll
  for (int nt = 0; nt < 4; ++nt) {
    f32x4 g3c = *(const f32x4*)(g3 + cb[nt]);
    f32x4 b3c = *(const f32x4*)(be3 + cb[nt]);
    z[nt] = (xo[nt] - mean3) * rstd3 * g3c + b3c;
  }
  short8 za = packfrag(z[0], z[1]);
  short8 zb = packfrag(z[2], z[3]);

  const int seq = sbase + s;
  const int bi2 = seq / 4800, prr = seq % 4800;
  const int phh = prr / 80, pww = prr % 80;
  const int obase = (bi2 * 16 * 480 + phh * 8) * 640 + pww * 8;
  const short* wob = wimg_g + 48 * 512;  // W_out frag images (128KB, L2-hot)

#pragma unroll 4
  for (int ntg = 0; ntg < 64; ++ntg) {
    short8 a0 = *(const short8*)&wob[(ntg * 2 + 0) * 512 + lane * 8];
    short8 a1 = *(const short8*)&wob[(ntg * 2 + 1) * 512 + lane * 8];
    int o0 = ntg * 16 + qd * 4;
    f32x4 acc = *(const f32x4*)(b_out + o0);
    acc = MFMA16(a0, za, acc);
    acc = MFMA16(a1, zb, acc);
    int c = o0 >> 6, pi = (o0 >> 3) & 7, pj = o0 & 7;
    *(f32x4*)&y[obase + c * 307200 + pi * 640 + pj] = acc;
  }
#undef WF
}

// ---------------------------------------------------------------------------
extern "C" void kernel_launch(void* const* d_in, const int* in_sizes, int n_in,
                              void* d_out, int out_size, void* d_ws, size_t ws_size,
                              hipStream_t stream) {
  const float* x       = (const float*)d_in[0];
  const float* W_embed = (const float*)d_in[1];
  const float* b_embed = (const float*)d_in[2];
  const float* g1      = (const float*)d_in[3];
  const float* beta1   = (const float*)d_in[4];
  const float* Lre     = (const float*)d_in[5];
  const float* Lim     = (const float*)d_in[6];
  const float* Bre     = (const float*)d_in[7];
  const float* Bim     = (const float*)d_in[8];
  const float* Cre     = (const float*)d_in[9];
  const float* Cim     = (const float*)d_in[10];
  const float* Dv      = (const float*)d_in[11];
  const float* lstep   = (const float*)d_in[12];
  const float* g2      = (const float*)d_in[13];
  const float* beta2   = (const float*)d_in[14];
  const float* W_enc   = (const float*)d_in[15];
  const float* W_dec   = (const float*)d_in[16];
  const float* g3      = (const float*)d_in[17];
  const float* beta3   = (const float*)d_in[18];
  const float* W_out   = (const float*)d_in[19];
  const float* b_out   = (const float*)d_in[20];
  float* y = (float*)d_out;

  short* wimg = (short*)d_ws;                          // 176 KB frag images
  float* bu0 = (float*)((char*)d_ws + 176 * 1024);     // 256 B

  k0_prep<<<dim3(45), dim3(256), 0, stream>>>(W_embed, g1, beta1, Lre, Lim,
                                              Bre, Bim, Cre, Cim, lstep,
                                              W_enc, W_dec, W_out, wimg, bu0);
  k1_fused<<<dim3(600), dim3(256), 0, stream>>>(x, wimg, bu0, Lre, Lim, lstep,
                                                g1, beta1, b_embed, Dv, g2,
                                                beta2, g3, beta3, b_out, y);
}